// Round 1
// baseline (795.274 us; speedup 1.0000x reference)
//
#include <hip/hip_runtime.h>
#include <math.h>

#define FIN 512
#define FH  64
#define FO  32

__global__ __launch_bounds__(256) void k_deg_init(float* __restrict__ deg, int n) {
  int i = blockIdx.x * 256 + threadIdx.x;
  if (i < n) deg[i] = 1.0f;
}

__global__ __launch_bounds__(256) void k_deg_hist(const int* __restrict__ dst,
                                                  float* __restrict__ deg, int E) {
  int i = blockIdx.x * 256 + threadIdx.x;
  if (i < E) atomicAdd(&deg[dst[i]], 1.0f);
}

__global__ __launch_bounds__(256) void k_dinv(float* __restrict__ deg, int n) {
  int i = blockIdx.x * 256 + threadIdx.x;
  if (i < n) deg[i] = 1.0f / sqrtf(deg[i]);
}

// GEMM1: P1[n][64] = dinv[n] * (x[n] @ W1); also writes agg1 = P1 (self-loop init).
// Block: 64 rows x 64 cols, 256 threads, each thread 4 rows (stride 16) x 4 cols.
__global__ __launch_bounds__(256) void k_gemm1(const float* __restrict__ x,
                                               const float* __restrict__ W1,
                                               const float* __restrict__ dinv,
                                               float* __restrict__ P1,
                                               float* __restrict__ agg1, int n) {
  __shared__ float xs[64][20];   // 64 rows x 16 k (pad 20: 2-way max on reads)
  __shared__ float wsm[16][68];  // 16 k x 64 cols (pad 68)
  int t = threadIdx.x;
  int tr = t & 15, tc = t >> 4;       // tr: row lane 0..15, tc: col group 0..15
  int lr = t >> 2, lk4 = t & 3;       // xs staging: row 0..63, float4 idx 0..3
  int wk = t >> 4, wc4 = t & 15;      // ws staging: k 0..15, col4 0..15
  int rowBase = blockIdx.x * 64;
  int xr = rowBase + lr; if (xr >= n) xr = n - 1;
  const float* xrow = x + (size_t)xr * FIN + lk4 * 4;

  float4 acc[4];
  #pragma unroll
  for (int i = 0; i < 4; i++) { acc[i].x = 0.f; acc[i].y = 0.f; acc[i].z = 0.f; acc[i].w = 0.f; }

  for (int kt = 0; kt < FIN; kt += 16) {
    float4 xv = *(const float4*)(xrow + kt);
    float4 wv = *(const float4*)(W1 + (size_t)(kt + wk) * FH + wc4 * 4);
    *(float4*)&xs[lr][lk4 * 4] = xv;
    *(float4*)&wsm[wk][wc4 * 4] = wv;
    __syncthreads();
    #pragma unroll
    for (int k0 = 0; k0 < 16; k0 += 4) {
      float4 wb0 = *(float4*)&wsm[k0 + 0][tc * 4];
      float4 wb1 = *(float4*)&wsm[k0 + 1][tc * 4];
      float4 wb2 = *(float4*)&wsm[k0 + 2][tc * 4];
      float4 wb3 = *(float4*)&wsm[k0 + 3][tc * 4];
      #pragma unroll
      for (int i = 0; i < 4; i++) {
        float4 a = *(float4*)&xs[tr + 16 * i][k0];
        acc[i].x += a.x * wb0.x + a.y * wb1.x + a.z * wb2.x + a.w * wb3.x;
        acc[i].y += a.x * wb0.y + a.y * wb1.y + a.z * wb2.y + a.w * wb3.y;
        acc[i].z += a.x * wb0.z + a.y * wb1.z + a.z * wb2.z + a.w * wb3.z;
        acc[i].w += a.x * wb0.w + a.y * wb1.w + a.z * wb2.w + a.w * wb3.w;
      }
    }
    __syncthreads();
  }

  #pragma unroll
  for (int i = 0; i < 4; i++) {
    int row = rowBase + tr + 16 * i;
    if (row < n) {
      float dv = dinv[row];
      float4 o;
      o.x = dv * acc[i].x; o.y = dv * acc[i].y; o.z = dv * acc[i].z; o.w = dv * acc[i].w;
      *(float4*)(P1 + (size_t)row * FH + tc * 4) = o;
      *(float4*)(agg1 + (size_t)row * FH + tc * 4) = o;
    }
  }
}

// scatter layer1: one wave per edge, lane = feature dim (64)
__global__ __launch_bounds__(256) void k_scat64(const int* __restrict__ ei,
                                                const float* __restrict__ P1,
                                                float* __restrict__ agg1, int E) {
  long long gid = (long long)blockIdx.x * 256 + threadIdx.x;
  int e = (int)(gid >> 6);
  int lane = threadIdx.x & 63;
  if (e >= E) return;
  int s = ei[e];
  int d = ei[E + e];
  float v = P1[(size_t)s * FH + lane];
  atomicAdd(agg1 + (size_t)d * FH + lane, v);
}

// GEMM2 with fused relu+bias on input: h = relu(dinv[r]*agg1[r]+b1);
// P2[n][32] = dinv[n]*(h@W2); also agg2 = P2 (self-loop init).
// Wave handles 2 rows: lanes 0..31 row p*2, lanes 32..63 row p*2+1.
__global__ __launch_bounds__(256) void k_gemm2(const float* __restrict__ agg1,
                                               const float* __restrict__ W2,
                                               const float* __restrict__ dinv,
                                               const float* __restrict__ b1,
                                               float* __restrict__ P2,
                                               float* __restrict__ agg2, int n) {
  int lane = threadIdx.x & 63;
  int c = lane & 31;
  int half = lane >> 5;
  float w[64];
  #pragma unroll
  for (int j = 0; j < 64; j++) w[j] = W2[j * FO + c];
  float bc0 = b1[c], bc1 = b1[32 + c];

  int gw = (blockIdx.x * 256 + threadIdx.x) >> 6;
  int nw = (gridDim.x * 256) >> 6;
  int npair = (n + 1) >> 1;
  for (int p = gw; p < npair; p += nw) {
    int row = p * 2 + half;
    bool ok = row < n;
    int r = ok ? row : n - 1;
    float dv = dinv[r];
    float v0 = fmaxf(dv * agg1[(size_t)r * FH + c] + bc0, 0.f);
    float v1 = fmaxf(dv * agg1[(size_t)r * FH + 32 + c] + bc1, 0.f);
    float acc = 0.f;
    #pragma unroll
    for (int j = 0; j < 32; j++) {
      float hv = __shfl(v0, (lane & 32) | j, 64);
      acc += hv * w[j];
    }
    #pragma unroll
    for (int j = 0; j < 32; j++) {
      float hv = __shfl(v1, (lane & 32) | j, 64);
      acc += hv * w[32 + j];
    }
    if (ok) {
      float o = dv * acc;
      P2[(size_t)row * FO + c] = o;
      agg2[(size_t)row * FO + c] = o;
    }
  }
}

// scatter layer2: 2 edges per wave, 32 lanes each
__global__ __launch_bounds__(256) void k_scat32(const int* __restrict__ ei,
                                                const float* __restrict__ P2,
                                                float* __restrict__ agg2, int E) {
  long long gid = (long long)blockIdx.x * 256 + threadIdx.x;
  int wv = (int)(gid >> 6);
  int lane = threadIdx.x & 63;
  int half = lane >> 5;
  int c = lane & 31;
  int e = wv * 2 + half;
  if (e >= E) return;
  int s = ei[e];
  int d = ei[E + e];
  float v = P2[(size_t)s * FO + c];
  atomicAdd(agg2 + (size_t)d * FO + c, v);
}

// final: o = dinv[v]*agg2[v] + b2; log_softmax over 32. 2 rows per wave.
__global__ __launch_bounds__(256) void k_final(const float* __restrict__ agg2,
                                               const float* __restrict__ dinv,
                                               const float* __restrict__ b2,
                                               float* __restrict__ out, int n) {
  long long gid = (long long)blockIdx.x * 256 + threadIdx.x;
  int wv = (int)(gid >> 6);
  int lane = threadIdx.x & 63;
  int half = lane >> 5;
  int c = lane & 31;
  int row = wv * 2 + half;
  if (row >= n) return;
  float v = dinv[row] * agg2[(size_t)row * FO + c] + b2[c];
  float m = v;
  #pragma unroll
  for (int off = 16; off > 0; off >>= 1) m = fmaxf(m, __shfl_xor(m, off, 64));
  float e = expf(v - m);
  float s = e;
  #pragma unroll
  for (int off = 16; off > 0; off >>= 1) s += __shfl_xor(s, off, 64);
  out[(size_t)row * FO + c] = v - m - logf(s);
}

extern "C" void kernel_launch(void* const* d_in, const int* in_sizes, int n_in,
                              void* d_out, int out_size, void* d_ws, size_t ws_size,
                              hipStream_t stream) {
  const float* x  = (const float*)d_in[0];
  const int*   ei = (const int*)d_in[1];
  const float* W1 = (const float*)d_in[2];
  const float* b1 = (const float*)d_in[3];
  const float* W2 = (const float*)d_in[4];
  const float* b2 = (const float*)d_in[5];
  const int N = in_sizes[0] / FIN;
  const int E = in_sizes[1] / 2;
  float* out = (float*)d_out;
  float* ws = (float*)d_ws;

  size_t NP = ((size_t)N + 63) & ~(size_t)63;
  float* dinv = ws;                       // N (deg -> dinv in place)
  float* P1   = dinv + NP;                // N*64
  float* agg1 = P1 + (size_t)N * FH;      // N*64
  float* P2   = agg1 + (size_t)N * FH;    // N*32
  float* agg2 = P2 + (size_t)N * FO;      // N*32

  k_deg_init<<<(N + 255) / 256, 256, 0, stream>>>(dinv, N);
  k_deg_hist<<<(E + 255) / 256, 256, 0, stream>>>(ei + E, dinv, E);
  k_dinv<<<(N + 255) / 256, 256, 0, stream>>>(dinv, N);
  k_gemm1<<<(N + 63) / 64, 256, 0, stream>>>(x, W1, dinv, P1, agg1, N);
  k_scat64<<<(int)(((long long)E * 64 + 255) / 256), 256, 0, stream>>>(ei, P1, agg1, E);
  k_gemm2<<<2048, 256, 0, stream>>>(agg1, W2, dinv, b1, P2, agg2, N);
  {
    long long waves32 = ((long long)E + 1) / 2;
    k_scat32<<<(int)((waves32 + 3) / 4), 256, 0, stream>>>(ei, P2, agg2, E);
  }
  {
    int waves = (N + 1) / 2;
    k_final<<<(waves + 3) / 4, 256, 0, stream>>>(agg2, dinv, b2, out, N);
  }
}

// Round 2
// 498.604 us; speedup vs baseline: 1.5950x; 1.5950x over previous
//
#include <hip/hip_runtime.h>
#include <math.h>

#define FIN 512
#define FH  64
#define FO  32

// zero 2N ints (deg + cursor, contiguous)
__global__ __launch_bounds__(256) void k_zero(int* __restrict__ p, int n2) {
  int i = blockIdx.x * 256 + threadIdx.x;
  if (i < n2) p[i] = 0;
}

__global__ __launch_bounds__(256) void k_deg_hist(const int* __restrict__ dst,
                                                  int* __restrict__ deg, int E) {
  int i = blockIdx.x * 256 + threadIdx.x;
  if (i < E) atomicAdd(&deg[dst[i]], 1);
}

__global__ __launch_bounds__(256) void k_dinv(const int* __restrict__ deg,
                                              float* __restrict__ dinv, int n) {
  int i = blockIdx.x * 256 + threadIdx.x;
  if (i < n) dinv[i] = rsqrtf((float)(deg[i] + 1));  // +1 self loop
}

// exclusive scan of deg within each 256-block -> rowoff; block total -> bsum
__global__ __launch_bounds__(256) void k_scan_block(const int* __restrict__ deg,
                                                    int* __restrict__ rowoff,
                                                    int* __restrict__ bsum, int n) {
  __shared__ int s[256];
  int t = threadIdx.x;
  int i = blockIdx.x * 256 + t;
  int v = (i < n) ? deg[i] : 0;
  s[t] = v;
  __syncthreads();
  #pragma unroll
  for (int off = 1; off < 256; off <<= 1) {
    int tmp = (t >= off) ? s[t - off] : 0;
    __syncthreads();
    s[t] += tmp;
    __syncthreads();
  }
  if (i < n) rowoff[i] = s[t] - v;
  if (t == 255) bsum[blockIdx.x] = s[255];
}

// single-block exclusive scan over block sums (nb <= ~400)
__global__ __launch_bounds__(256) void k_scan_bsum(int* __restrict__ bsum, int nb) {
  __shared__ int s[256];
  int t = threadIdx.x;
  int carry = 0;
  for (int base = 0; base < nb; base += 256) {
    int idx = base + t;
    int v = (idx < nb) ? bsum[idx] : 0;
    s[t] = v;
    __syncthreads();
    #pragma unroll
    for (int off = 1; off < 256; off <<= 1) {
      int tmp = (t >= off) ? s[t - off] : 0;
      __syncthreads();
      s[t] += tmp;
      __syncthreads();
    }
    if (idx < nb) bsum[idx] = s[t] - v + carry;
    carry += s[255];  // uniform across threads
    __syncthreads();
  }
}

__global__ __launch_bounds__(256) void k_scan_add(int* __restrict__ rowoff,
                                                  const int* __restrict__ bsum, int n) {
  int i = blockIdx.x * 256 + threadIdx.x;
  if (i < n) rowoff[i] += bsum[blockIdx.x];
}

__global__ __launch_bounds__(256) void k_csr_fill(const int* __restrict__ ei,
                                                  const int* __restrict__ rowoff,
                                                  int* __restrict__ cursor,
                                                  int* __restrict__ csr, int E) {
  int e = blockIdx.x * 256 + threadIdx.x;
  if (e >= E) return;
  int s = ei[e];
  int d = ei[E + e];
  int pos = atomicAdd(&cursor[d], 1);
  csr[rowoff[d] + pos] = s;
}

// GEMM1: P1[n][64] = dinv[n] * (x[n] @ W1)
__global__ __launch_bounds__(256) void k_gemm1(const float* __restrict__ x,
                                               const float* __restrict__ W1,
                                               const float* __restrict__ dinv,
                                               float* __restrict__ P1, int n) {
  __shared__ float xs[64][20];
  __shared__ float wsm[16][68];
  int t = threadIdx.x;
  int tr = t & 15, tc = t >> 4;
  int lr = t >> 2, lk4 = t & 3;
  int wk = t >> 4, wc4 = t & 15;
  int rowBase = blockIdx.x * 64;
  int xr = rowBase + lr; if (xr >= n) xr = n - 1;
  const float* xrow = x + (size_t)xr * FIN + lk4 * 4;

  float4 acc[4];
  #pragma unroll
  for (int i = 0; i < 4; i++) { acc[i].x = 0.f; acc[i].y = 0.f; acc[i].z = 0.f; acc[i].w = 0.f; }

  for (int kt = 0; kt < FIN; kt += 16) {
    float4 xv = *(const float4*)(xrow + kt);
    float4 wv = *(const float4*)(W1 + (size_t)(kt + wk) * FH + wc4 * 4);
    *(float4*)&xs[lr][lk4 * 4] = xv;
    *(float4*)&wsm[wk][wc4 * 4] = wv;
    __syncthreads();
    #pragma unroll
    for (int k0 = 0; k0 < 16; k0 += 4) {
      float4 wb0 = *(float4*)&wsm[k0 + 0][tc * 4];
      float4 wb1 = *(float4*)&wsm[k0 + 1][tc * 4];
      float4 wb2 = *(float4*)&wsm[k0 + 2][tc * 4];
      float4 wb3 = *(float4*)&wsm[k0 + 3][tc * 4];
      #pragma unroll
      for (int i = 0; i < 4; i++) {
        float4 a = *(float4*)&xs[tr + 16 * i][k0];
        acc[i].x += a.x * wb0.x + a.y * wb1.x + a.z * wb2.x + a.w * wb3.x;
        acc[i].y += a.x * wb0.y + a.y * wb1.y + a.z * wb2.y + a.w * wb3.y;
        acc[i].z += a.x * wb0.z + a.y * wb1.z + a.z * wb2.z + a.w * wb3.z;
        acc[i].w += a.x * wb0.w + a.y * wb1.w + a.z * wb2.w + a.w * wb3.w;
      }
    }
    __syncthreads();
  }

  #pragma unroll
  for (int i = 0; i < 4; i++) {
    int row = rowBase + tr + 16 * i;
    if (row < n) {
      float dv = dinv[row];
      float4 o;
      o.x = dv * acc[i].x; o.y = dv * acc[i].y; o.z = dv * acc[i].z; o.w = dv * acc[i].w;
      *(float4*)(P1 + (size_t)row * FH + tc * 4) = o;
    }
  }
}

// gather layer1: one wave per dst node, lane = dim (64)
__global__ __launch_bounds__(256) void k_gather1(const float* __restrict__ P1,
                                                 const int* __restrict__ csr,
                                                 const int* __restrict__ rowoff,
                                                 const int* __restrict__ deg,
                                                 float* __restrict__ agg1, int n) {
  int wv = (blockIdx.x * 256 + threadIdx.x) >> 6;
  int lane = threadIdx.x & 63;
  if (wv >= n) return;
  int base = rowoff[wv];
  int cnt = deg[wv];
  float acc = P1[(size_t)wv * FH + lane];  // self loop
  for (int j0 = 0; j0 < cnt; j0 += 64) {
    int idx = (j0 + lane < cnt) ? csr[base + j0 + lane] : 0;
    int m = cnt - j0; if (m > 64) m = 64;
    for (int j = 0; j < m; j++) {
      int u = __shfl(idx, j, 64);
      acc += P1[(size_t)u * FH + lane];
    }
  }
  agg1[(size_t)wv * FH + lane] = acc;
}

// GEMM2: h = relu(dinv[r]*agg1[r]+b1); P2 = dinv[r]*(h@W2). Wave = 2 rows.
__global__ __launch_bounds__(256) void k_gemm2(const float* __restrict__ agg1,
                                               const float* __restrict__ W2,
                                               const float* __restrict__ dinv,
                                               const float* __restrict__ b1,
                                               float* __restrict__ P2, int n) {
  int lane = threadIdx.x & 63;
  int c = lane & 31;
  int half = lane >> 5;
  float w[64];
  #pragma unroll
  for (int j = 0; j < 64; j++) w[j] = W2[j * FO + c];
  float bc0 = b1[c], bc1 = b1[32 + c];

  int gw = (blockIdx.x * 256 + threadIdx.x) >> 6;
  int nw = (gridDim.x * 256) >> 6;
  int npair = (n + 1) >> 1;
  for (int p = gw; p < npair; p += nw) {
    int row = p * 2 + half;
    bool ok = row < n;
    int r = ok ? row : n - 1;
    float dv = dinv[r];
    float v0 = fmaxf(dv * agg1[(size_t)r * FH + c] + bc0, 0.f);
    float v1 = fmaxf(dv * agg1[(size_t)r * FH + 32 + c] + bc1, 0.f);
    float acc = 0.f;
    #pragma unroll
    for (int j = 0; j < 32; j++) {
      float hv = __shfl(v0, (lane & 32) | j, 64);
      acc += hv * w[j];
    }
    #pragma unroll
    for (int j = 0; j < 32; j++) {
      float hv = __shfl(v1, (lane & 32) | j, 64);
      acc += hv * w[32 + j];
    }
    if (ok) P2[(size_t)row * FO + c] = dv * acc;
  }
}

// gather layer2 + bias + log_softmax, half-wave (32 lanes) per dst node
__global__ __launch_bounds__(256) void k_gather2_final(const float* __restrict__ P2,
                                                       const int* __restrict__ csr,
                                                       const int* __restrict__ rowoff,
                                                       const int* __restrict__ deg,
                                                       const float* __restrict__ dinv,
                                                       const float* __restrict__ b2,
                                                       float* __restrict__ out, int n) {
  int gid = blockIdx.x * 256 + threadIdx.x;
  int wv = gid >> 6;
  int lane = threadIdx.x & 63;
  int half = lane >> 5;
  int c = lane & 31;
  int v = wv * 2 + half;
  if (v >= n) return;
  int base = rowoff[v];
  int cnt = deg[v];
  float acc = P2[(size_t)v * FO + c];  // self loop
  for (int j0 = 0; j0 < cnt; j0 += 32) {
    int idx = (j0 + c < cnt) ? csr[base + j0 + c] : 0;
    int m = cnt - j0; if (m > 32) m = 32;
    for (int j = 0; j < m; j++) {
      int u = __shfl(idx, (lane & 32) | j, 64);
      acc += P2[(size_t)u * FO + c];
    }
  }
  float val = dinv[v] * acc + b2[c];
  float mx = val;
  #pragma unroll
  for (int off = 16; off > 0; off >>= 1) mx = fmaxf(mx, __shfl_xor(mx, off, 64));
  float ex = expf(val - mx);
  float s = ex;
  #pragma unroll
  for (int off = 16; off > 0; off >>= 1) s += __shfl_xor(s, off, 64);
  out[(size_t)v * FO + c] = val - mx - logf(s);
}

extern "C" void kernel_launch(void* const* d_in, const int* in_sizes, int n_in,
                              void* d_out, int out_size, void* d_ws, size_t ws_size,
                              hipStream_t stream) {
  const float* x  = (const float*)d_in[0];
  const int*   ei = (const int*)d_in[1];
  const float* W1 = (const float*)d_in[2];
  const float* b1 = (const float*)d_in[3];
  const float* W2 = (const float*)d_in[4];
  const float* b2 = (const float*)d_in[5];
  const int N = in_sizes[0] / FIN;
  const int E = in_sizes[1] / 2;
  float* out = (float*)d_out;

  size_t NP = ((size_t)N + 63) & ~(size_t)63;
  int nb = (N + 255) / 256;

  int*   deg    = (int*)d_ws;            // N
  int*   cursor = deg + NP;              // N  (contiguous with deg for k_zero)
  int*   rowoff = cursor + NP;           // N
  int*   bsum   = rowoff + NP;           // nb (<=512)
  float* dinv   = (float*)(bsum + 512);  // N
  int*   csr    = (int*)(dinv + NP);     // E
  size_t EP = ((size_t)E + 63) & ~(size_t)63;
  float* P1   = (float*)(csr + EP);      // N*64
  float* agg1 = P1 + NP * FH;            // N*64
  float* P2   = agg1 + NP * FH;          // N*32

  k_zero<<<(int)((2 * NP + 255) / 256), 256, 0, stream>>>(deg, (int)(2 * NP));
  k_deg_hist<<<(E + 255) / 256, 256, 0, stream>>>(ei + E, deg, E);
  k_dinv<<<(N + 255) / 256, 256, 0, stream>>>(deg, dinv, N);
  k_scan_block<<<nb, 256, 0, stream>>>(deg, rowoff, bsum, N);
  k_scan_bsum<<<1, 256, 0, stream>>>(bsum, nb);
  k_scan_add<<<nb, 256, 0, stream>>>(rowoff, bsum, N);
  k_csr_fill<<<(E + 255) / 256, 256, 0, stream>>>(ei, rowoff, cursor, csr, E);
  k_gemm1<<<(N + 63) / 64, 256, 0, stream>>>(x, W1, dinv, P1, N);
  k_gather1<<<(int)(((long long)N * 64 + 255) / 256), 256, 0, stream>>>(P1, csr, rowoff, deg, agg1, N);
  k_gemm2<<<2048, 256, 0, stream>>>(agg1, W2, dinv, b1, P2, N);
  k_gather2_final<<<(int)(((long long)N * 32 + 255) / 256), 256, 0, stream>>>(P2, csr, rowoff, deg, dinv, b2, out, N);
}

// Round 3
// 374.551 us; speedup vs baseline: 2.1233x; 1.3312x over previous
//
#include <hip/hip_runtime.h>
#include <math.h>

#define FIN 512
#define FH  64
#define FO  32

typedef __bf16 bf16_t;
typedef bf16_t bf16x8 __attribute__((ext_vector_type(8)));
typedef float  f32x4  __attribute__((ext_vector_type(4)));

// zero 2N ints (deg + cursor, contiguous)
__global__ __launch_bounds__(256) void k_zero(int* __restrict__ p, int n2) {
  int i = blockIdx.x * 256 + threadIdx.x;
  if (i < n2) p[i] = 0;
}

__global__ __launch_bounds__(256) void k_deg_hist(const int* __restrict__ dst,
                                                  int* __restrict__ deg, int E) {
  int i = blockIdx.x * 256 + threadIdx.x;
  if (i < E) atomicAdd(&deg[dst[i]], 1);
}

__global__ __launch_bounds__(256) void k_dinv(const int* __restrict__ deg,
                                              float* __restrict__ dinv, int n) {
  int i = blockIdx.x * 256 + threadIdx.x;
  if (i < n) dinv[i] = rsqrtf((float)(deg[i] + 1));  // +1 self loop
}

__global__ __launch_bounds__(256) void k_scan_block(const int* __restrict__ deg,
                                                    int* __restrict__ rowoff,
                                                    int* __restrict__ bsum, int n) {
  __shared__ int s[256];
  int t = threadIdx.x;
  int i = blockIdx.x * 256 + t;
  int v = (i < n) ? deg[i] : 0;
  s[t] = v;
  __syncthreads();
  #pragma unroll
  for (int off = 1; off < 256; off <<= 1) {
    int tmp = (t >= off) ? s[t - off] : 0;
    __syncthreads();
    s[t] += tmp;
    __syncthreads();
  }
  if (i < n) rowoff[i] = s[t] - v;
  if (t == 255) bsum[blockIdx.x] = s[255];
}

__global__ __launch_bounds__(256) void k_scan_bsum(int* __restrict__ bsum, int nb) {
  __shared__ int s[256];
  int t = threadIdx.x;
  int carry = 0;
  for (int base = 0; base < nb; base += 256) {
    int idx = base + t;
    int v = (idx < nb) ? bsum[idx] : 0;
    s[t] = v;
    __syncthreads();
    #pragma unroll
    for (int off = 1; off < 256; off <<= 1) {
      int tmp = (t >= off) ? s[t - off] : 0;
      __syncthreads();
      s[t] += tmp;
      __syncthreads();
    }
    if (idx < nb) bsum[idx] = s[t] - v + carry;
    carry += s[255];
    __syncthreads();
  }
}

__global__ __launch_bounds__(256) void k_scan_add(int* __restrict__ rowoff,
                                                  const int* __restrict__ bsum, int n) {
  int i = blockIdx.x * 256 + threadIdx.x;
  if (i < n) rowoff[i] += bsum[blockIdx.x];
}

__global__ __launch_bounds__(256) void k_csr_fill(const int* __restrict__ ei,
                                                  const int* __restrict__ rowoff,
                                                  int* __restrict__ cursor,
                                                  int* __restrict__ csr, int E) {
  int e = blockIdx.x * 256 + threadIdx.x;
  if (e >= E) return;
  int s = ei[e];
  int d = ei[E + e];
  int pos = atomicAdd(&cursor[d], 1);
  csr[rowoff[d] + pos] = s;
}

// W1 [512][64] fp32 -> W1T [64][512] bf16 (read-coalesced)
__global__ __launch_bounds__(256) void k_w1t(const float* __restrict__ W1,
                                             bf16_t* __restrict__ w1t) {
  int i = blockIdx.x * 256 + threadIdx.x;  // 32768
  int c = i & 63, k = i >> 6;
  w1t[(size_t)c * FIN + k] = (bf16_t)W1[(size_t)k * FH + c];
}

// GEMM1 via MFMA bf16: P1[n][64] = dinv[n] * (x[n] @ W1)
// Block: 256 threads = 4 waves; each wave OWNS 16 rows (no __syncthreads).
// Per k-tile of 32: wave stages its 16x32 fp32 -> bf16 in private LDS
// (row stride 40 bf16 = 80B: 2-way bank alias only), reads A-frag b128,
// loads 4 B-frags from L2-resident W1T, 4 MFMAs.
__global__ __launch_bounds__(256) void k_gemm1(const float* __restrict__ x,
                                               const bf16_t* __restrict__ w1t,
                                               const float* __restrict__ dinv,
                                               float* __restrict__ P1, int n) {
  __shared__ __align__(16) bf16_t alds[4][16 * 40];
  int t = threadIdx.x;
  int w = t >> 6;        // wave 0..3
  int l = t & 63;        // lane
  int r = l >> 2;        // staging row-in-wave 0..15
  int kg = l & 3;        // staging k-group (8 floats)
  int rowBase = blockIdx.x * 64 + w * 16;

  int gr = rowBase + r; if (gr >= n) gr = n - 1;
  const float* xp = x + (size_t)gr * FIN + kg * 8;

  int fr = l & 15;       // fragment row / col
  int fk = l >> 4;       // fragment k-group (8 k)
  const bf16_t* wbase = w1t + (size_t)fr * FIN + fk * 8;

  f32x4 acc0 = {0.f, 0.f, 0.f, 0.f};
  f32x4 acc1 = {0.f, 0.f, 0.f, 0.f};
  f32x4 acc2 = {0.f, 0.f, 0.f, 0.f};
  f32x4 acc3 = {0.f, 0.f, 0.f, 0.f};

  bf16_t* myw = &alds[w][r * 40 + kg * 8];
  const bf16_t* myr = &alds[w][fr * 40 + fk * 8];

  for (int kt = 0; kt < FIN; kt += 32) {
    float4 a0 = *(const float4*)(xp + kt);
    float4 a1 = *(const float4*)(xp + kt + 4);
    bf16x8 av;
    av[0] = (bf16_t)a0.x; av[1] = (bf16_t)a0.y; av[2] = (bf16_t)a0.z; av[3] = (bf16_t)a0.w;
    av[4] = (bf16_t)a1.x; av[5] = (bf16_t)a1.y; av[6] = (bf16_t)a1.z; av[7] = (bf16_t)a1.w;
    *(bf16x8*)myw = av;                        // intra-wave only; lgkmcnt ordering
    bf16x8 af = *(const bf16x8*)myr;
    bf16x8 b0 = *(const bf16x8*)(wbase + kt);
    bf16x8 b1 = *(const bf16x8*)(wbase + (size_t)16 * FIN + kt);
    bf16x8 b2 = *(const bf16x8*)(wbase + (size_t)32 * FIN + kt);
    bf16x8 b3 = *(const bf16x8*)(wbase + (size_t)48 * FIN + kt);
    acc0 = __builtin_amdgcn_mfma_f32_16x16x32_bf16(af, b0, acc0, 0, 0, 0);
    acc1 = __builtin_amdgcn_mfma_f32_16x16x32_bf16(af, b1, acc1, 0, 0, 0);
    acc2 = __builtin_amdgcn_mfma_f32_16x16x32_bf16(af, b2, acc2, 0, 0, 0);
    acc3 = __builtin_amdgcn_mfma_f32_16x16x32_bf16(af, b3, acc3, 0, 0, 0);
  }

  // C/D layout: col = lane&15, row = (lane>>4)*4 + reg
  #pragma unroll
  for (int rg = 0; rg < 4; rg++) {
    int grow = rowBase + fk * 4 + rg;
    if (grow < n) {
      float dv = dinv[grow];
      float* prow = P1 + (size_t)grow * FH + fr;
      prow[0]  = dv * acc0[rg];
      prow[16] = dv * acc1[rg];
      prow[32] = dv * acc2[rg];
      prow[48] = dv * acc3[rg];
    }
  }
}

// gather layer1: wave per dst node; 4 edge-slots x 16 lanes of float4.
__global__ __launch_bounds__(256) void k_gather1(const float* __restrict__ P1,
                                                 const int* __restrict__ csr,
                                                 const int* __restrict__ rowoff,
                                                 const int* __restrict__ deg,
                                                 float* __restrict__ agg1, int n) {
  int wv = (blockIdx.x * 256 + threadIdx.x) >> 6;
  if (wv >= n) return;
  int lane = threadIdx.x & 63;
  int es = lane >> 4;    // edge slot 0..3
  int dg = lane & 15;    // float4 group
  int base = rowoff[wv];
  int cnt = deg[wv];
  const float4* P1v = (const float4*)P1;

  float4 a = {0.f, 0.f, 0.f, 0.f}, b = {0.f, 0.f, 0.f, 0.f};
  if (es == 0) a = P1v[(size_t)wv * 16 + dg];  // self loop
  int j = 0;
  for (; j + 8 <= cnt; j += 8) {
    int u0 = csr[base + j + es];
    int u1 = csr[base + j + 4 + es];
    float4 v0 = P1v[(size_t)u0 * 16 + dg];
    float4 v1 = P1v[(size_t)u1 * 16 + dg];
    a.x += v0.x; a.y += v0.y; a.z += v0.z; a.w += v0.w;
    b.x += v1.x; b.y += v1.y; b.z += v1.z; b.w += v1.w;
  }
  for (; j < cnt; j += 4) {
    if (j + es < cnt) {
      int u = csr[base + j + es];
      float4 v = P1v[(size_t)u * 16 + dg];
      a.x += v.x; a.y += v.y; a.z += v.z; a.w += v.w;
    }
  }
  a.x += b.x; a.y += b.y; a.z += b.z; a.w += b.w;
  #pragma unroll
  for (int off = 16; off <= 32; off <<= 1) {
    a.x += __shfl_xor(a.x, off, 64);
    a.y += __shfl_xor(a.y, off, 64);
    a.z += __shfl_xor(a.z, off, 64);
    a.w += __shfl_xor(a.w, off, 64);
  }
  if (es == 0) ((float4*)agg1)[(size_t)wv * 16 + dg] = a;
}

// GEMM2: h = relu(dinv[r]*agg1[r]+b1); P2 = dinv[r]*(h@W2). Wave = 2 rows.
__global__ __launch_bounds__(256) void k_gemm2(const float* __restrict__ agg1,
                                               const float* __restrict__ W2,
                                               const float* __restrict__ dinv,
                                               const float* __restrict__ b1,
                                               float* __restrict__ P2, int n) {
  int lane = threadIdx.x & 63;
  int c = lane & 31;
  int half = lane >> 5;
  float w[64];
  #pragma unroll
  for (int j = 0; j < 64; j++) w[j] = W2[j * FO + c];
  float bc0 = b1[c], bc1 = b1[32 + c];

  int gw = (blockIdx.x * 256 + threadIdx.x) >> 6;
  int nw = (gridDim.x * 256) >> 6;
  int npair = (n + 1) >> 1;
  for (int p = gw; p < npair; p += nw) {
    int row = p * 2 + half;
    bool ok = row < n;
    int r = ok ? row : n - 1;
    float dv = dinv[r];
    float v0 = fmaxf(dv * agg1[(size_t)r * FH + c] + bc0, 0.f);
    float v1 = fmaxf(dv * agg1[(size_t)r * FH + 32 + c] + bc1, 0.f);
    float acc = 0.f;
    #pragma unroll
    for (int j = 0; j < 32; j++) {
      float hv = __shfl(v0, (lane & 32) | j, 64);
      acc += hv * w[j];
    }
    #pragma unroll
    for (int j = 0; j < 32; j++) {
      float hv = __shfl(v1, (lane & 32) | j, 64);
      acc += hv * w[32 + j];
    }
    if (ok) P2[(size_t)row * FO + c] = dv * acc;
  }
}

// gather layer2 + bias + log_softmax: wave per node; 8 slots x 8 float4 lanes.
__global__ __launch_bounds__(256) void k_gather2_final(const float* __restrict__ P2,
                                                       const int* __restrict__ csr,
                                                       const int* __restrict__ rowoff,
                                                       const int* __restrict__ deg,
                                                       const float* __restrict__ dinv,
                                                       const float* __restrict__ b2,
                                                       float* __restrict__ out, int n) {
  int v = (blockIdx.x * 256 + threadIdx.x) >> 6;
  if (v >= n) return;
  int lane = threadIdx.x & 63;
  int es = lane >> 3;    // edge slot 0..7
  int dg = lane & 7;     // float4 group over 32
  int base = rowoff[v];
  int cnt = deg[v];
  const float4* P2v = (const float4*)P2;

  float4 a = {0.f, 0.f, 0.f, 0.f}, b = {0.f, 0.f, 0.f, 0.f};
  if (es == 0) a = P2v[(size_t)v * 8 + dg];  // self loop
  int j = 0;
  for (; j + 16 <= cnt; j += 16) {
    int u0 = csr[base + j + es];
    int u1 = csr[base + j + 8 + es];
    float4 v0 = P2v[(size_t)u0 * 8 + dg];
    float4 v1 = P2v[(size_t)u1 * 8 + dg];
    a.x += v0.x; a.y += v0.y; a.z += v0.z; a.w += v0.w;
    b.x += v1.x; b.y += v1.y; b.z += v1.z; b.w += v1.w;
  }
  for (; j < cnt; j += 8) {
    if (j + es < cnt) {
      int u = csr[base + j + es];
      float4 vv = P2v[(size_t)u * 8 + dg];
      a.x += vv.x; a.y += vv.y; a.z += vv.z; a.w += vv.w;
    }
  }
  a.x += b.x; a.y += b.y; a.z += b.z; a.w += b.w;
  #pragma unroll
  for (int off = 8; off <= 32; off <<= 1) {
    a.x += __shfl_xor(a.x, off, 64);
    a.y += __shfl_xor(a.y, off, 64);
    a.z += __shfl_xor(a.z, off, 64);
    a.w += __shfl_xor(a.w, off, 64);
  }
  float dv = dinv[v];
  float4 bb = ((const float4*)b2)[dg];
  float4 val;
  val.x = dv * a.x + bb.x; val.y = dv * a.y + bb.y;
  val.z = dv * a.z + bb.z; val.w = dv * a.w + bb.w;
  float m = fmaxf(fmaxf(val.x, val.y), fmaxf(val.z, val.w));
  #pragma unroll
  for (int off = 1; off <= 4; off <<= 1) m = fmaxf(m, __shfl_xor(m, off, 64));
  float s = expf(val.x - m) + expf(val.y - m) + expf(val.z - m) + expf(val.w - m);
  #pragma unroll
  for (int off = 1; off <= 4; off <<= 1) s += __shfl_xor(s, off, 64);
  float lse = m + logf(s);
  if (es == 0) {
    float4 o;
    o.x = val.x - lse; o.y = val.y - lse; o.z = val.z - lse; o.w = val.w - lse;
    ((float4*)out)[(size_t)v * 8 + dg] = o;
  }
}

extern "C" void kernel_launch(void* const* d_in, const int* in_sizes, int n_in,
                              void* d_out, int out_size, void* d_ws, size_t ws_size,
                              hipStream_t stream) {
  const float* x  = (const float*)d_in[0];
  const int*   ei = (const int*)d_in[1];
  const float* W1 = (const float*)d_in[2];
  const float* b1 = (const float*)d_in[3];
  const float* W2 = (const float*)d_in[4];
  const float* b2 = (const float*)d_in[5];
  const int N = in_sizes[0] / FIN;
  const int E = in_sizes[1] / 2;
  float* out = (float*)d_out;

  size_t NP = ((size_t)N + 63) & ~(size_t)63;
  size_t EP = ((size_t)E + 63) & ~(size_t)63;
  int nb = (N + 255) / 256;

  int*   deg    = (int*)d_ws;            // N
  int*   cursor = deg + NP;              // N (contiguous with deg for k_zero)
  int*   rowoff = cursor + NP;           // N
  int*   bsum   = rowoff + NP;           // <=512
  float* dinv   = (float*)(bsum + 512);  // N
  int*   csr    = (int*)(dinv + NP);     // E
  bf16_t* w1t   = (bf16_t*)(csr + EP);   // 64*512 bf16 = 64KB
  float* P1   = (float*)(w1t + (size_t)FH * FIN);  // N*64
  float* agg1 = P1 + NP * FH;            // N*64
  float* P2   = agg1 + NP * FH;          // N*32

  k_zero<<<(int)((2 * NP + 255) / 256), 256, 0, stream>>>(deg, (int)(2 * NP));
  k_deg_hist<<<(E + 255) / 256, 256, 0, stream>>>(ei + E, deg, E);
  k_dinv<<<(N + 255) / 256, 256, 0, stream>>>(deg, dinv, N);
  k_scan_block<<<nb, 256, 0, stream>>>(deg, rowoff, bsum, N);
  k_scan_bsum<<<1, 256, 0, stream>>>(bsum, nb);
  k_scan_add<<<nb, 256, 0, stream>>>(rowoff, bsum, N);
  k_csr_fill<<<(E + 255) / 256, 256, 0, stream>>>(ei, rowoff, cursor, csr, E);
  k_w1t<<<(FIN * FH + 255) / 256, 256, 0, stream>>>(W1, w1t);
  k_gemm1<<<(N + 63) / 64, 256, 0, stream>>>(x, w1t, dinv, P1, N);
  k_gather1<<<(int)(((long long)N * 64 + 255) / 256), 256, 0, stream>>>(P1, csr, rowoff, deg, agg1, N);
  k_gemm2<<<2048, 256, 0, stream>>>(agg1, W2, dinv, b1, P2, N);
  k_gather2_final<<<(int)(((long long)N * 64 + 255) / 256), 256, 0, stream>>>(P2, csr, rowoff, deg, dinv, b2, out, N);
}

// Round 4
// 336.373 us; speedup vs baseline: 2.3643x; 1.1135x over previous
//
#include <hip/hip_runtime.h>
#include <math.h>

#define FIN 512
#define FH  64
#define FO  32

typedef __bf16 bf16_t;
typedef bf16_t bf16x8 __attribute__((ext_vector_type(8)));
typedef bf16_t bf16x4 __attribute__((ext_vector_type(4)));
typedef float  f32x4  __attribute__((ext_vector_type(4)));

// fused init: zero deg+cursor (2*NP ints), build W1T bf16 [64][512], W2T bf16 [32][64]
__global__ __launch_bounds__(256) void k_init(int* __restrict__ p, int n2,
                                              const float* __restrict__ W1,
                                              bf16_t* __restrict__ w1t,
                                              const float* __restrict__ W2,
                                              bf16_t* __restrict__ w2t) {
  int i = blockIdx.x * 256 + threadIdx.x;
  if (i < n2) p[i] = 0;
  if (i < FIN * FH) {  // write-contiguous W1T: c = i>>9, k = i&511
    int c = i >> 9, k = i & 511;
    w1t[i] = (bf16_t)W1[(size_t)k * FH + c];
  }
  if (i < FH * FO) {   // write-contiguous W2T: c = i>>6, k = i&63
    int c = i >> 6, k = i & 63;
    w2t[i] = (bf16_t)W2[(size_t)k * FO + c];
  }
}

__global__ __launch_bounds__(256) void k_deg_hist(const int* __restrict__ dst,
                                                  int* __restrict__ deg, int E) {
  int i = blockIdx.x * 256 + threadIdx.x;
  if (i < E) atomicAdd(&deg[dst[i]], 1);
}

// block-local exclusive scan of deg -> rowoff, block total -> bsum; dinv fused
__global__ __launch_bounds__(256) void k_scan_block(const int* __restrict__ deg,
                                                    int* __restrict__ rowoff,
                                                    int* __restrict__ bsum,
                                                    float* __restrict__ dinv, int n) {
  __shared__ int s[256];
  int t = threadIdx.x;
  int i = blockIdx.x * 256 + t;
  int v = (i < n) ? deg[i] : 0;
  s[t] = v;
  __syncthreads();
  #pragma unroll
  for (int off = 1; off < 256; off <<= 1) {
    int tmp = (t >= off) ? s[t - off] : 0;
    __syncthreads();
    s[t] += tmp;
    __syncthreads();
  }
  if (i < n) {
    rowoff[i] = s[t] - v;
    dinv[i] = rsqrtf((float)(v + 1));  // +1 self loop
  }
  if (t == 255) bsum[blockIdx.x] = s[255];
}

__global__ __launch_bounds__(256) void k_scan_bsum(int* __restrict__ bsum, int nb) {
  __shared__ int s[256];
  int t = threadIdx.x;
  int carry = 0;
  for (int base = 0; base < nb; base += 256) {
    int idx = base + t;
    int v = (idx < nb) ? bsum[idx] : 0;
    s[t] = v;
    __syncthreads();
    #pragma unroll
    for (int off = 1; off < 256; off <<= 1) {
      int tmp = (t >= off) ? s[t - off] : 0;
      __syncthreads();
      s[t] += tmp;
      __syncthreads();
    }
    if (idx < nb) bsum[idx] = s[t] - v + carry;
    carry += s[255];
    __syncthreads();
  }
}

__global__ __launch_bounds__(256) void k_scan_add(int* __restrict__ rowoff,
                                                  const int* __restrict__ bsum, int n) {
  int i = blockIdx.x * 256 + threadIdx.x;
  if (i < n) rowoff[i] += bsum[blockIdx.x];
}

__global__ __launch_bounds__(256) void k_csr_fill(const int* __restrict__ ei,
                                                  const int* __restrict__ rowoff,
                                                  int* __restrict__ cursor,
                                                  int* __restrict__ csr, int E) {
  int e = blockIdx.x * 256 + threadIdx.x;
  if (e >= E) return;
  int s = ei[e];
  int d = ei[E + e];
  int pos = atomicAdd(&cursor[d], 1);
  csr[rowoff[d] + pos] = s;
}

// GEMM1 via MFMA, no LDS: P1[n][64] (bf16) = dinv[n] * (x[n] @ W1)
// 4 waves/block, wave owns 16 rows. Lane loads its own A-frag from global.
__global__ __launch_bounds__(256) void k_gemm1(const float* __restrict__ x,
                                               const bf16_t* __restrict__ w1t,
                                               const float* __restrict__ dinv,
                                               bf16_t* __restrict__ P1, int n) {
  int t = threadIdx.x;
  int w = t >> 6, l = t & 63;
  int rowBase = blockIdx.x * 64 + w * 16;
  int fr = l & 15, fk = l >> 4;
  int ar = rowBase + fr; if (ar >= n) ar = n - 1;
  const float* xp = x + (size_t)ar * FIN + fk * 8;
  const bf16_t* wb = w1t + (size_t)fr * FIN + fk * 8;

  f32x4 acc0 = {0.f, 0.f, 0.f, 0.f};
  f32x4 acc1 = {0.f, 0.f, 0.f, 0.f};
  f32x4 acc2 = {0.f, 0.f, 0.f, 0.f};
  f32x4 acc3 = {0.f, 0.f, 0.f, 0.f};

  #pragma unroll 4
  for (int kt = 0; kt < FIN; kt += 32) {
    float4 a0 = *(const float4*)(xp + kt);
    float4 a1 = *(const float4*)(xp + kt + 4);
    bf16x8 av;
    av[0] = (bf16_t)a0.x; av[1] = (bf16_t)a0.y; av[2] = (bf16_t)a0.z; av[3] = (bf16_t)a0.w;
    av[4] = (bf16_t)a1.x; av[5] = (bf16_t)a1.y; av[6] = (bf16_t)a1.z; av[7] = (bf16_t)a1.w;
    bf16x8 b0 = *(const bf16x8*)(wb + kt);
    bf16x8 b1 = *(const bf16x8*)(wb + (size_t)16 * FIN + kt);
    bf16x8 b2 = *(const bf16x8*)(wb + (size_t)32 * FIN + kt);
    bf16x8 b3 = *(const bf16x8*)(wb + (size_t)48 * FIN + kt);
    acc0 = __builtin_amdgcn_mfma_f32_16x16x32_bf16(av, b0, acc0, 0, 0, 0);
    acc1 = __builtin_amdgcn_mfma_f32_16x16x32_bf16(av, b1, acc1, 0, 0, 0);
    acc2 = __builtin_amdgcn_mfma_f32_16x16x32_bf16(av, b2, acc2, 0, 0, 0);
    acc3 = __builtin_amdgcn_mfma_f32_16x16x32_bf16(av, b3, acc3, 0, 0, 0);
  }

  // C/D: col = lane&15 (=fr), row = fk*4 + reg
  #pragma unroll
  for (int rg = 0; rg < 4; rg++) {
    int grow = rowBase + fk * 4 + rg;
    if (grow < n) {
      float dv = dinv[grow];
      bf16_t* prow = P1 + (size_t)grow * FH + fr;
      prow[0]  = (bf16_t)(dv * acc0[rg]);
      prow[16] = (bf16_t)(dv * acc1[rg]);
      prow[32] = (bf16_t)(dv * acc2[rg]);
      prow[48] = (bf16_t)(dv * acc3[rg]);
    }
  }
}

// gather1 + fused relu/bias/dinv: h[v] = relu(dinv[v]*sum + b1), bf16 out.
// Wave per dst node: 4 edge-slots x 16 lanes of bf16x4 (8B).
__global__ __launch_bounds__(256) void k_gather1(const bf16_t* __restrict__ P1,
                                                 const int* __restrict__ csr,
                                                 const int* __restrict__ rowoff,
                                                 const int* __restrict__ deg,
                                                 const float* __restrict__ dinv,
                                                 const float* __restrict__ b1,
                                                 bf16_t* __restrict__ h, int n) {
  int wv = (blockIdx.x * 256 + threadIdx.x) >> 6;
  if (wv >= n) return;
  int lane = threadIdx.x & 63;
  int es = lane >> 4;    // edge slot 0..3
  int dg = lane & 15;    // bf16x4 group (dims dg*4..dg*4+3)
  int base = rowoff[wv];
  int cnt = deg[wv];
  const bf16x4* P1v = (const bf16x4*)P1;

  float4 a = {0.f, 0.f, 0.f, 0.f}, b = {0.f, 0.f, 0.f, 0.f};
  if (es == 0) {
    bf16x4 sv = P1v[(size_t)wv * 16 + dg];  // self loop
    a.x = (float)sv[0]; a.y = (float)sv[1]; a.z = (float)sv[2]; a.w = (float)sv[3];
  }
  int j = 0;
  for (; j + 8 <= cnt; j += 8) {
    int u0 = csr[base + j + es];
    int u1 = csr[base + j + 4 + es];
    bf16x4 v0 = P1v[(size_t)u0 * 16 + dg];
    bf16x4 v1 = P1v[(size_t)u1 * 16 + dg];
    a.x += (float)v0[0]; a.y += (float)v0[1]; a.z += (float)v0[2]; a.w += (float)v0[3];
    b.x += (float)v1[0]; b.y += (float)v1[1]; b.z += (float)v1[2]; b.w += (float)v1[3];
  }
  for (; j < cnt; j += 4) {
    if (j + es < cnt) {
      int u = csr[base + j + es];
      bf16x4 v = P1v[(size_t)u * 16 + dg];
      a.x += (float)v[0]; a.y += (float)v[1]; a.z += (float)v[2]; a.w += (float)v[3];
    }
  }
  a.x += b.x; a.y += b.y; a.z += b.z; a.w += b.w;
  #pragma unroll
  for (int off = 16; off <= 32; off <<= 1) {
    a.x += __shfl_xor(a.x, off, 64);
    a.y += __shfl_xor(a.y, off, 64);
    a.z += __shfl_xor(a.z, off, 64);
    a.w += __shfl_xor(a.w, off, 64);
  }
  if (es == 0) {
    float dv = dinv[wv];
    float4 bb = ((const float4*)b1)[dg];
    bf16x4 hv;
    hv[0] = (bf16_t)fmaxf(dv * a.x + bb.x, 0.f);
    hv[1] = (bf16_t)fmaxf(dv * a.y + bb.y, 0.f);
    hv[2] = (bf16_t)fmaxf(dv * a.z + bb.z, 0.f);
    hv[3] = (bf16_t)fmaxf(dv * a.w + bb.w, 0.f);
    ((bf16x4*)h)[(size_t)wv * 16 + dg] = hv;
  }
}

// GEMM2 via MFMA: P2[n][32] (bf16) = dinv[n] * (h[n] @ W2)
__global__ __launch_bounds__(256) void k_gemm2(const bf16_t* __restrict__ h,
                                               const bf16_t* __restrict__ w2t,
                                               const float* __restrict__ dinv,
                                               bf16_t* __restrict__ P2, int n) {
  int t = threadIdx.x;
  int w = t >> 6, l = t & 63;
  int rowBase = blockIdx.x * 64 + w * 16;
  int fr = l & 15, fk = l >> 4;
  int ar = rowBase + fr; if (ar >= n) ar = n - 1;
  const bf16_t* hp = h + (size_t)ar * FH + fk * 8;
  const bf16_t* wb0 = w2t + (size_t)fr * FH + fk * 8;
  const bf16_t* wb1 = w2t + (size_t)(fr + 16) * FH + fk * 8;

  f32x4 acc0 = {0.f, 0.f, 0.f, 0.f};
  f32x4 acc1 = {0.f, 0.f, 0.f, 0.f};
  #pragma unroll
  for (int kt = 0; kt < FH; kt += 32) {
    bf16x8 af = *(const bf16x8*)(hp + kt);
    bf16x8 b0 = *(const bf16x8*)(wb0 + kt);
    bf16x8 b1 = *(const bf16x8*)(wb1 + kt);
    acc0 = __builtin_amdgcn_mfma_f32_16x16x32_bf16(af, b0, acc0, 0, 0, 0);
    acc1 = __builtin_amdgcn_mfma_f32_16x16x32_bf16(af, b1, acc1, 0, 0, 0);
  }
  #pragma unroll
  for (int rg = 0; rg < 4; rg++) {
    int grow = rowBase + fk * 4 + rg;
    if (grow < n) {
      float dv = dinv[grow];
      P2[(size_t)grow * FO + fr]      = (bf16_t)(dv * acc0[rg]);
      P2[(size_t)grow * FO + fr + 16] = (bf16_t)(dv * acc1[rg]);
    }
  }
}

// gather2 + bias + log_softmax: wave per node; 8 slots x 8 lanes of bf16x4.
__global__ __launch_bounds__(256) void k_gather2_final(const bf16_t* __restrict__ P2,
                                                       const int* __restrict__ csr,
                                                       const int* __restrict__ rowoff,
                                                       const int* __restrict__ deg,
                                                       const float* __restrict__ dinv,
                                                       const float* __restrict__ b2,
                                                       float* __restrict__ out, int n) {
  int v = (blockIdx.x * 256 + threadIdx.x) >> 6;
  if (v >= n) return;
  int lane = threadIdx.x & 63;
  int es = lane >> 3;    // edge slot 0..7
  int dg = lane & 7;     // bf16x4 group over 32 dims
  int base = rowoff[v];
  int cnt = deg[v];
  const bf16x4* P2v = (const bf16x4*)P2;

  float4 a = {0.f, 0.f, 0.f, 0.f}, b = {0.f, 0.f, 0.f, 0.f};
  if (es == 0) {
    bf16x4 sv = P2v[(size_t)v * 8 + dg];  // self loop
    a.x = (float)sv[0]; a.y = (float)sv[1]; a.z = (float)sv[2]; a.w = (float)sv[3];
  }
  int j = 0;
  for (; j + 16 <= cnt; j += 16) {
    int u0 = csr[base + j + es];
    int u1 = csr[base + j + 8 + es];
    bf16x4 v0 = P2v[(size_t)u0 * 8 + dg];
    bf16x4 v1 = P2v[(size_t)u1 * 8 + dg];
    a.x += (float)v0[0]; a.y += (float)v0[1]; a.z += (float)v0[2]; a.w += (float)v0[3];
    b.x += (float)v1[0]; b.y += (float)v1[1]; b.z += (float)v1[2]; b.w += (float)v1[3];
  }
  for (; j < cnt; j += 8) {
    if (j + es < cnt) {
      int u = csr[base + j + es];
      bf16x4 vv = P2v[(size_t)u * 8 + dg];
      a.x += (float)vv[0]; a.y += (float)vv[1]; a.z += (float)vv[2]; a.w += (float)vv[3];
    }
  }
  a.x += b.x; a.y += b.y; a.z += b.z; a.w += b.w;
  #pragma unroll
  for (int off = 8; off <= 32; off <<= 1) {
    a.x += __shfl_xor(a.x, off, 64);
    a.y += __shfl_xor(a.y, off, 64);
    a.z += __shfl_xor(a.z, off, 64);
    a.w += __shfl_xor(a.w, off, 64);
  }
  float dv = dinv[v];
  float4 bb = ((const float4*)b2)[dg];
  float4 val;
  val.x = dv * a.x + bb.x; val.y = dv * a.y + bb.y;
  val.z = dv * a.z + bb.z; val.w = dv * a.w + bb.w;
  float m = fmaxf(fmaxf(val.x, val.y), fmaxf(val.z, val.w));
  #pragma unroll
  for (int off = 1; off <= 4; off <<= 1) m = fmaxf(m, __shfl_xor(m, off, 64));
  float s = expf(val.x - m) + expf(val.y - m) + expf(val.z - m) + expf(val.w - m);
  #pragma unroll
  for (int off = 1; off <= 4; off <<= 1) s += __shfl_xor(s, off, 64);
  float lse = m + logf(s);
  if (es == 0) {
    float4 o;
    o.x = val.x - lse; o.y = val.y - lse; o.z = val.z - lse; o.w = val.w - lse;
    ((float4*)out)[(size_t)v * 8 + dg] = o;
  }
}

extern "C" void kernel_launch(void* const* d_in, const int* in_sizes, int n_in,
                              void* d_out, int out_size, void* d_ws, size_t ws_size,
                              hipStream_t stream) {
  const float* x  = (const float*)d_in[0];
  const int*   ei = (const int*)d_in[1];
  const float* W1 = (const float*)d_in[2];
  const float* b1 = (const float*)d_in[3];
  const float* W2 = (const float*)d_in[4];
  const float* b2 = (const float*)d_in[5];
  const int N = in_sizes[0] / FIN;
  const int E = in_sizes[1] / 2;
  float* out = (float*)d_out;

  size_t NP = ((size_t)N + 63) & ~(size_t)63;
  size_t EP = ((size_t)E + 63) & ~(size_t)63;
  int nb = (N + 255) / 256;

  int*    deg    = (int*)d_ws;             // NP
  int*    cursor = deg + NP;               // NP (contiguous with deg for zeroing)
  int*    rowoff = cursor + NP;            // NP
  int*    bsum   = rowoff + NP;            // 512
  float*  dinv   = (float*)(bsum + 512);   // NP
  int*    csr    = (int*)(dinv + NP);      // EP
  bf16_t* w1t    = (bf16_t*)(csr + EP);    // 64*512
  bf16_t* w2t    = w1t + (size_t)FH * FIN; // 32*64
  bf16_t* P1     = w2t + (size_t)FO * FH;  // NP*64
  bf16_t* h      = P1 + NP * FH;           // NP*64
  bf16_t* P2     = h + NP * FH;            // NP*32

  int initN = (int)(2 * NP);
  if (initN < FIN * FH) initN = FIN * FH;
  k_init<<<(initN + 255) / 256, 256, 0, stream>>>(deg, (int)(2 * NP), W1, w1t, W2, w2t);
  k_deg_hist<<<(E + 255) / 256, 256, 0, stream>>>(ei + E, deg, E);
  k_scan_block<<<nb, 256, 0, stream>>>(deg, rowoff, bsum, dinv, N);
  k_scan_bsum<<<1, 256, 0, stream>>>(bsum, nb);
  k_scan_add<<<nb, 256, 0, stream>>>(rowoff, bsum, N);
  k_csr_fill<<<(E + 255) / 256, 256, 0, stream>>>(ei, rowoff, cursor, csr, E);
  k_gemm1<<<(N + 63) / 64, 256, 0, stream>>>(x, w1t, dinv, P1, N);
  k_gather1<<<(int)(((long long)N * 64 + 255) / 256), 256, 0, stream>>>(P1, csr, rowoff, deg, dinv, b1, h, N);
  k_gemm2<<<(N + 63) / 64, 256, 0, stream>>>(h, w2t, dinv, P2, N);
  k_gather2_final<<<(int)(((long long)N * 64 + 255) / 256), 256, 0, stream>>>(P2, csr, rowoff, deg, dinv, b2, out, N);
}